// Round 4
// baseline (1730.157 us; speedup 1.0000x reference)
//
#include <hip/hip_runtime.h>
#include <math.h>

#define HWs 6400

__device__ __forceinline__ float sigm_(float x){ return 1.0f/(1.0f+__expf(-x)); }
__device__ __forceinline__ float silu_(float x){ return x/(1.0f+__expf(-x)); }

// ---------------- weight transpose: w[OC][Cin][3][3] -> Wt[K][Npad] ----------------
// k-order: rmajor=0 -> k = c*9+r ;  rmajor=1 -> k = r*Cin+c
__global__ void wt_kernel(const float* __restrict__ w, float* __restrict__ Wt,
                          int Cin, int OC, int Npad, int K, int rmajor){
  int idx = blockIdx.x*256 + threadIdx.x;
  if (idx >= K*Npad) return;
  int k = idx / Npad, n = idx - k*Npad;
  int c, r;
  if (rmajor){ r = k / Cin; c = k - r*Cin; } else { c = k / 9; r = k - c*9; }
  Wt[idx] = (n < OC) ? w[((size_t)n*Cin + c)*9 + r] : 0.0f;
}

// ---------------- bn scale/shift prep ----------------
// out layout: [0:16] sc1 [16:32] sh1 [32:48] sc2 [48:64] sh2 [64:192] scF [192:320] shF
__global__ void bnprep_kernel(const float* __restrict__ bn1, const float* __restrict__ bn2,
                              const float* __restrict__ bnf, float* __restrict__ o){
  int t = threadIdx.x;
  if (t < 16){
    float s = bn1[t] / sqrtf(bn1[48+t] + 1e-5f);
    o[t] = s; o[16+t] = bn1[16+t] - bn1[32+t]*s;
  } else if (t < 32){
    int i = t-16;
    float s = bn2[i] / sqrtf(bn2[48+i] + 1e-5f);
    o[32+i] = s; o[48+i] = bn2[16+i] - bn2[32+i]*s;
  } else if (t < 160){
    int i = t-32;
    float s = bnf[i] / sqrtf(bnf[384+i] + 1e-5f);
    o[64+i] = s; o[192+i] = bnf[128+i] - bnf[256+i]*s;
  }
}

// ---------------- implicit-GEMM conv ----------------
// MODE 0: 3x3 conv, A = concat(A0[Cin0 ch], A1[Cin-Cin0 ch]), k = c*9+r
// MODE 1: deformable gather on A0 (=ir, 128ch), offsets/mask from offp, k = r*128+c
// MODE 2: like MODE 0, but A-value scaled by g (c<Cin0) or 1-g (c>=Cin0); g from offp (1ch/batch)
// BN = 128 (NR=8) or 32 (NR=2). BM=64, BK=16, 256 threads, each 4xNR outputs.
// EPI: 0 = +bias(e0) ; 1 = silu(x+bias) ; 2 = silu(x*sc+sh) ; 3 = silu(x*sc+sh)+rs*res
template<int MODE, int BN, int EPI>
__global__ __launch_bounds__(256)
void gemm_conv(const float* __restrict__ A0, const float* __restrict__ A1,
               int Cin0, int Cin,
               const float* __restrict__ offp,
               const float* __restrict__ Wt, int K,
               float* __restrict__ Out, int Nout,
               const float* __restrict__ e0, const float* __restrict__ e1,
               const float* __restrict__ res, const float* __restrict__ rsp)
{
  constexpr int NR = BN/16;
  __shared__ __align__(16) float As[16*64];
  __shared__ __align__(16) float Bs[16*BN];
  const int tid = threadIdx.x;
  const int mb  = blockIdx.x * 64;

  // staging pixel (one A-row per thread)
  const int ml = tid & 63;
  const int m  = mb + ml;
  const int b  = m / HWs;
  const int p  = m - b*HWs;
  const int y  = p / 80;
  const int x  = p - y*80;
  const int aoff = y*80 + x;
  const int kk0 = tid >> 6;   // wave-uniform

  float acc[4][NR];
  #pragma unroll
  for (int i=0;i<4;i++)
    #pragma unroll
    for (int j=0;j<NR;j++) acc[i][j] = 0.0f;

  // MODE0/2 per-slot (c,r) state, wave-uniform
  int sc[4], sr[4];
  if (MODE != 1){
    #pragma unroll
    for (int s=0;s<4;s++){ int kk = kk0 + 4*s; sc[s] = kk/9; sr[s] = kk - (kk/9)*9; }
  }
  const float* abase0 = A0 + (size_t)b*Cin0*HWs;
  const float* abase1 = (MODE!=1) ? (A1 + ((size_t)b*(Cin-Cin0) - Cin0)*HWs) : A0;
  const float* gb = (MODE==2) ? (offp + (size_t)b*HWs) : A0;   // gate plane

  // MODE1 cached bilinear state
  float w00=0.f,w01=0.f,w10=0.f,w11=0.f;
  int o00=0,o01=0,o10=0,o11=0;
  const float* irb = A0 + (size_t)b*128*HWs;          // MODE1
  const float* ofb = (MODE==1) ? (offp + (size_t)b*27*HWs + aoff) : A0;

  for (int k0 = 0; k0 < K; k0 += 16){
    float areg[4];
    if (MODE != 1){
      #pragma unroll
      for (int s=0;s<4;s++){
        int c = sc[s], r = sr[s];
        int dy = r/3, dx = r - (r/3)*3;
        int yy = y + dy - 1, xx = x + dx - 1;
        const float* base = (c < Cin0) ? abase0 : abase1;
        bool v = ((unsigned)yy < 80u) & ((unsigned)xx < 80u);
        if (MODE == 0){
          areg[s] = v ? base[(size_t)c*HWs + yy*80 + xx] : 0.0f;
        } else {
          if (v){
            float gv = gb[yy*80 + xx];
            float scale = (c < Cin0) ? gv : (1.0f - gv);
            areg[s] = scale * base[(size_t)c*HWs + yy*80 + xx];
          } else areg[s] = 0.0f;
        }
        sc[s] += 1; sr[s] += 7; if (sr[s] >= 9){ sr[s] -= 9; sc[s] += 1; }
      }
    } else {
      if ((k0 & 127) == 0){
        int r = k0 >> 7;
        float oy = ofb[(size_t)(2*r)*HWs];
        float ox = ofb[(size_t)(2*r+1)*HWs];
        float mk = sigm_(ofb[(size_t)(18+r)*HWs]);
        int dy = r/3, dx = r - (r/3)*3;
        float ys = oy + (float)(y + dy - 1);
        float xs = ox + (float)(x + dx - 1);
        float yf = floorf(ys), xf = floorf(xs);
        float wy = ys - yf, wx = xs - xf;
        int y0 = (int)yf, x0 = (int)xf;
        float vy0 = ((unsigned)y0     < 80u) ? 1.f : 0.f;
        float vy1 = ((unsigned)(y0+1) < 80u) ? 1.f : 0.f;
        float vx0 = ((unsigned)x0     < 80u) ? 1.f : 0.f;
        float vx1 = ((unsigned)(x0+1) < 80u) ? 1.f : 0.f;
        w00 = (1.f-wy)*(1.f-wx)*mk*vy0*vx0;
        w01 = (1.f-wy)*wx      *mk*vy0*vx1;
        w10 = wy      *(1.f-wx)*mk*vy1*vx0;
        w11 = wy      *wx      *mk*vy1*vx1;
        int cy0 = min(max(y0  ,0),79), cy1 = min(max(y0+1,0),79);
        int cx0 = min(max(x0  ,0),79), cx1 = min(max(x0+1,0),79);
        o00 = cy0*80+cx0; o01 = cy0*80+cx1; o10 = cy1*80+cx0; o11 = cy1*80+cx1;
      }
      const float* irb2 = irb + (size_t)(k0 & 127)*HWs;
      #pragma unroll
      for (int s=0;s<4;s++){
        const float* pl = irb2 + (size_t)(kk0 + 4*s)*HWs;
        areg[s] = w00*pl[o00] + w01*pl[o01] + w10*pl[o10] + w11*pl[o11];
      }
    }
    // B-tile: flat contiguous copy Wt[k0*BN .. k0*BN + 16*BN)
    const float4* wsrc = (const float4*)(Wt + (size_t)k0*BN);
    float4 br0, br1;
    if (BN == 128){ br0 = wsrc[tid]; br1 = wsrc[tid + 256]; }
    else          { if (tid < 128) br0 = wsrc[tid]; }

    __syncthreads();
    #pragma unroll
    for (int s=0;s<4;s++) As[(kk0 + 4*s)*64 + ml] = areg[s];
    float4* Bs4w = (float4*)Bs;
    if (BN == 128){ Bs4w[tid] = br0; Bs4w[tid+256] = br1; }
    else          { if (tid < 128) Bs4w[tid] = br0; }
    __syncthreads();

    const float4* As4 = (const float4*)As;
    const float4* Bs4 = (const float4*)Bs;
    #pragma unroll
    for (int kk=0;kk<16;kk++){
      float4 a = As4[kk*16 + (tid & 15)];
      float av[4] = {a.x,a.y,a.z,a.w};
      if (NR == 8){
        float4 b0 = Bs4[kk*32 + (tid>>4)*2];
        float4 b1 = Bs4[kk*32 + (tid>>4)*2 + 1];
        float bv[8] = {b0.x,b0.y,b0.z,b0.w,b1.x,b1.y,b1.z,b1.w};
        #pragma unroll
        for (int i=0;i<4;i++)
          #pragma unroll
          for (int j=0;j<8;j++) acc[i][j] = fmaf(av[i], bv[j], acc[i][j]);
      } else {
        const float2* Bs2 = (const float2*)Bs;
        float2 b0 = Bs2[kk*16 + (tid>>4)];
        float bv[2] = {b0.x, b0.y};
        #pragma unroll
        for (int i=0;i<4;i++)
          #pragma unroll
          for (int j=0;j<NR;j++) acc[i][j] = fmaf(av[i], bv[j], acc[i][j]);
      }
    }
    __syncthreads();
  }

  // epilogue + store (4 consecutive pixels per float4)
  const int cm = mb + (tid & 15)*4;
  const int cb = cm / HWs;
  const int cp = cm - cb*HWs;
  const int n0 = (tid >> 4) * NR;
  float rsv = 0.f;
  if (EPI == 3) rsv = rsp[0];
  #pragma unroll
  for (int j=0;j<NR;j++){
    int n = n0 + j;
    if (BN == 32 && n >= Nout) continue;
    float vv[4] = {acc[0][j], acc[1][j], acc[2][j], acc[3][j]};
    size_t ob = ((size_t)cb*Nout + n)*HWs + cp;
    if (EPI == 0){
      float bb = e0[n];
      #pragma unroll
      for (int i=0;i<4;i++) vv[i] += bb;
    } else if (EPI == 1){
      float bb = e0[n];
      #pragma unroll
      for (int i=0;i<4;i++) vv[i] = silu_(vv[i] + bb);
    } else if (EPI == 2){
      float s = e0[n], sh = e1[n];
      #pragma unroll
      for (int i=0;i<4;i++) vv[i] = silu_(fmaf(vv[i], s, sh));
    } else {
      float s = e0[n], sh = e1[n];
      float4 r4 = *(const float4*)(res + ob);
      float rr[4] = {r4.x,r4.y,r4.z,r4.w};
      #pragma unroll
      for (int i=0;i<4;i++) vv[i] = silu_(fmaf(vv[i], s, sh)) + rsv*rr[i];
    }
    float4 v; v.x=vv[0]; v.y=vv[1]; v.z=vv[2]; v.w=vv[3];
    *(float4*)(Out + ob) = v;
  }
}

// ---------------- gate conv1x1 256->16 + bn + silu ----------------
__global__ __launch_bounds__(256) void gate1_kernel(
  const float* __restrict__ rgb, const float* __restrict__ iral,
  const float* __restrict__ wg1, const float* __restrict__ bns,
  float* __restrict__ out)
{
  __shared__ float Ws[4096];   // [c][mc]
  int tid = threadIdx.x;
  for (int i = tid; i < 4096; i += 256){
    int mc = i >> 8, c = i & 255;
    Ws[c*16 + mc] = wg1[i];
  }
  __syncthreads();
  int idx = blockIdx.x*256 + tid;
  int b = idx / HWs, p = idx - b*HWs;
  const float* r0 = rgb  + (size_t)b*128*HWs + p;
  const float* i0 = iral + ((size_t)b*128 - 128)*HWs + p;
  float acc[16];
  #pragma unroll
  for (int mc=0;mc<16;mc++) acc[mc]=0.f;
  #pragma unroll 4
  for (int c=0;c<256;c++){
    float v = (c<128) ? r0[(size_t)c*HWs] : i0[(size_t)c*HWs];
    const float4* w4 = (const float4*)&Ws[c*16];
    #pragma unroll
    for (int q=0;q<4;q++){
      float4 w = w4[q];
      acc[q*4+0] = fmaf(v, w.x, acc[q*4+0]);
      acc[q*4+1] = fmaf(v, w.y, acc[q*4+1]);
      acc[q*4+2] = fmaf(v, w.z, acc[q*4+2]);
      acc[q*4+3] = fmaf(v, w.w, acc[q*4+3]);
    }
  }
  #pragma unroll
  for (int mc=0;mc<16;mc++){
    float t = fmaf(acc[mc], bns[mc], bns[16+mc]);
    out[((size_t)b*16+mc)*HWs + p] = silu_(t);
  }
}

// ---------------- gate depthwise3x3+bn+silu + conv1x1->1 + sigmoid ----------------
__global__ __launch_bounds__(256) void gate23_kernel(
  const float* __restrict__ g1b, const float* __restrict__ wg2,
  const float* __restrict__ wg3, const float* __restrict__ bg3,
  const float* __restrict__ bns, float* __restrict__ g)
{
  __shared__ float w2s[144], w3s[16], sc2[16], sh2[16];
  __shared__ float b3s;
  int tid = threadIdx.x;
  if (tid < 144) w2s[tid] = wg2[tid];
  if (tid < 16){ w3s[tid] = wg3[tid]; sc2[tid] = bns[32+tid]; sh2[tid] = bns[48+tid]; }
  if (tid == 0) b3s = bg3[0];
  __syncthreads();
  int idx = blockIdx.x*256 + tid;
  int b = idx / HWs, p = idx - b*HWs;
  int y = p/80, x = p - y*80;
  float acc = b3s;
  #pragma unroll
  for (int mc=0;mc<16;mc++){
    const float* base = g1b + ((size_t)b*16+mc)*HWs;
    float s = 0.f;
    #pragma unroll
    for (int r=0;r<9;r++){
      int dy = r/3, dx = r - (r/3)*3;
      int yy = y + dy - 1, xx = x + dx - 1;
      if (((unsigned)yy < 80u) & ((unsigned)xx < 80u))
        s = fmaf(base[yy*80+xx], w2s[mc*9+r], s);
    }
    float t = fmaf(s, sc2[mc], sh2[mc]);
    acc = fmaf(silu_(t), w3s[mc], acc);
  }
  g[idx] = sigm_(acc);
}

extern "C" void kernel_launch(void* const* d_in, const int* in_sizes, int n_in,
                              void* d_out, int out_size, void* d_ws, size_t ws_size,
                              hipStream_t stream)
{
  const float* rgb  = (const float*)d_in[0];
  const float* ir   = (const float*)d_in[1];
  const float* w1   = (const float*)d_in[2];
  const float* b1   = (const float*)d_in[3];
  const float* w2   = (const float*)d_in[4];
  const float* b2   = (const float*)d_in[5];
  const float* wd   = (const float*)d_in[6];
  const float* bd   = (const float*)d_in[7];
  const float* wg1  = (const float*)d_in[8];
  const float* bng1 = (const float*)d_in[9];
  const float* wg2  = (const float*)d_in[10];
  const float* bng2 = (const float*)d_in[11];
  const float* wg3  = (const float*)d_in[12];
  const float* bg3  = (const float*)d_in[13];
  const float* wf   = (const float*)d_in[14];
  const float* bnf  = (const float*)d_in[15];
  const float* rs   = (const float*)d_in[16];
  float* out = (float*)d_out;

  float* ws   = (float*)d_ws;
  float* hbuf = ws;                    // 6,553,600
  float* offb = hbuf + 6553600;        // 1,382,400
  float* iral = offb + 1382400;        // 6,553,600
  float* g1b  = iral + 6553600;        //   819,200
  float* gbuf = g1b  + 819200;         //    51,200
  float* Wt1  = gbuf + 51200;          //   294,912
  float* Wt2  = Wt1  + 294912;         //    36,864
  float* Wt3  = Wt2  + 36864;          //   147,456
  float* Wt4  = Wt3  + 147456;         //   294,912
  float* bns  = Wt4  + 294912;         //       320
  // total ~16.1M floats = ~64.5 MB

  bnprep_kernel<<<1, 256, 0, stream>>>(bng1, bng2, bnf, bns);
  wt_kernel<<<(294912+255)/256, 256, 0, stream>>>(w1, Wt1, 256, 128, 128, 2304, 0);
  wt_kernel<<<( 36864+255)/256, 256, 0, stream>>>(w2, Wt2, 128,  27,  32, 1152, 0);
  wt_kernel<<<(147456+255)/256, 256, 0, stream>>>(wd, Wt3, 128, 128, 128, 1152, 1);
  wt_kernel<<<(294912+255)/256, 256, 0, stream>>>(wf, Wt4, 256, 128, 128, 2304, 0);

  // h = silu(conv3x3(cat(rgb,ir), w_off1) + b_off1)
  gemm_conv<0,128,1><<<800, 256, 0, stream>>>(rgb, ir, 128, 256, nullptr,
      Wt1, 2304, hbuf, 128, b1, nullptr, nullptr, nullptr);
  // off = conv3x3(h, w_off2) + b_off2   (27 ch raw)
  gemm_conv<0,32,0><<<800, 256, 0, stream>>>(hbuf, hbuf, 128, 128, nullptr,
      Wt2, 1152, offb, 27, b2, nullptr, nullptr, nullptr);
  // ir_aligned = DCN(ir, offsets, mask) + b_dcn   (fused bilinear gather)
  gemm_conv<1,128,0><<<800, 256, 0, stream>>>(ir, ir, 128, 128, offb,
      Wt3, 1152, iral, 128, bd, nullptr, nullptr, nullptr);
  // gate path
  gate1_kernel<<<200, 256, 0, stream>>>(rgb, iral, wg1, bns, g1b);
  gate23_kernel<<<200, 256, 0, stream>>>(g1b, wg2, wg3, bg3, bns, gbuf);
  // out = silu(bn(conv3x3(concat(g*ir_al,(1-g)*rgb), w_f))) + res_scale*ir_aligned
  // (fused_in computed on the fly in MODE 2 — no fib buffer)
  gemm_conv<2,128,3><<<800, 256, 0, stream>>>(iral, rgb, 128, 256, gbuf,
      Wt4, 2304, out, 128, bns+64, bns+192, iral, rs);
}

// Round 7
// 1168.390 us; speedup vs baseline: 1.4808x; 1.4808x over previous
//
#include <hip/hip_runtime.h>
#include <math.h>

#define HWs 6400

typedef __attribute__((ext_vector_type(8))) short s8v;
typedef __attribute__((ext_vector_type(4))) float f4v;
typedef unsigned short ushortT;
typedef unsigned int uintT;

__device__ __forceinline__ float sigm_(float x){ return 1.0f/(1.0f+__expf(-x)); }
__device__ __forceinline__ float silu_(float x){ return x/(1.0f+__expf(-x)); }
__device__ __forceinline__ ushortT f2bf(float f){
  uintT u = __float_as_uint(f);
  u = (u + 0x7fffu + ((u>>16)&1u)) >> 16;
  return (ushortT)u;
}

// ---------------- weight prep: w -> Bt[n][k] bf16 ----------------
// rmajor=0: k = c*9+r  (identity over w's row)   rmajor=1 (Cin=128): k = r*128+c
__global__ void wtb_kernel(const float* __restrict__ w, ushortT* __restrict__ Bt,
                           int Cin, int OC, int Npad, int K, int rmajor){
  int idx = blockIdx.x*256 + threadIdx.x;
  if (idx >= Npad*K) return;
  int n = idx / K, k = idx - n*K;
  float v = 0.0f;
  if (n < OC){
    if (rmajor){ int r = k >> 7; int c = k & 127; v = w[((size_t)n*Cin + c)*9 + r]; }
    else       { v = w[(size_t)n*K + k]; }
  }
  Bt[idx] = f2bf(v);
}

// ---------------- bn scale/shift prep ----------------
// layout: [0:16] sc1 [16:32] sh1 [32:48] sc2 [48:64] sh2 [64:192] scF [192:320] shF
__global__ void bnprep_kernel(const float* __restrict__ bn1, const float* __restrict__ bn2,
                              const float* __restrict__ bnf, float* __restrict__ o){
  int t = threadIdx.x;
  if (t < 16){
    float s = bn1[t] / sqrtf(bn1[48+t] + 1e-5f);
    o[t] = s; o[16+t] = bn1[16+t] - bn1[32+t]*s;
  } else if (t < 32){
    int i = t-16;
    float s = bn2[i] / sqrtf(bn2[48+i] + 1e-5f);
    o[32+i] = s; o[48+i] = bn2[16+i] - bn2[32+i]*s;
  } else if (t < 160){
    int i = t-32;
    float s = bnf[i] / sqrtf(bnf[384+i] + 1e-5f);
    o[64+i] = s; o[192+i] = bnf[128+i] - bnf[256+i]*s;
  }
}

// ---------------- MFMA implicit-GEMM conv ----------------
// BM=128, BK=32, 256 thr = 4 waves.
// BN=128: wave grid 2x2, wave tile 64x64 (MF=NF=4). BN=32: waves 4x1, tile 32x32 (MF=NF=2).
// MODE 0: 3x3 conv on concat(A0[Cin0], A1[Cin-Cin0]), k=c*9+r
// MODE 1: deformable gather on A0 (=ir), offsets offp, k=r*128+c
// MODE 2: MODE0 with gate scaling: c<Cin0 -> g, else 1-g (g = offp, 1 plane/batch)
// EPI: 0 +bias ; 1 silu(x+bias) ; 2 silu(x*sc+sh) ; 3 silu(x*sc+sh)+rs*res
template<int MODE, int BN, int EPI>
__global__ __launch_bounds__(256)
void mconv(const float* __restrict__ A0, const float* __restrict__ A1,
           int Cin0, int Cin,
           const float* __restrict__ offp,
           const ushortT* __restrict__ Bt, int K,
           float* __restrict__ Out, int Nout,
           const float* __restrict__ e0, const float* __restrict__ e1,
           const float* __restrict__ res, const float* __restrict__ rsp)
{
  constexpr int MF = (BN==128)? 4 : 2;
  constexpr int NF = (BN==128)? 4 : 2;
  constexpr int BCH = (BN==128)? 2 : 1;       // B 16B-chunks per thread
  __shared__ ushortT As[128*40];
  __shared__ ushortT Bs[BN*40];

  const int tid = threadIdx.x;
  const int mb  = blockIdx.x * 128;
  const int b   = mb / HWs;                    // uniform (6400 % 128 == 0)

  // ---- staging ids: thread covers 16 k for one m ----
  const int g2 = tid >> 6;
  const int sm = (tid & 63) + ((g2 & 1) << 6); // 0..127
  const int sk = (g2 >> 1) << 4;               // 0 or 16
  const int m  = mb + sm;
  const int p  = m - b*HWs;
  const int y  = p / 80;
  const int x  = p - y*80;

  const float* a0p = A0 + (size_t)b*Cin0*HWs + p;
  const float* a1p = (MODE!=1)? (A1 + ((size_t)b*(Cin-Cin0) - (size_t)Cin0)*HWs + p) : A0;
  const float* gp  = (MODE==2)? (offp + (size_t)b*HWs + p) : A0;
  const float* ofb = (MODE==1)? (offp + (size_t)b*27*HWs + p) : A0;
  const float* irb = A0 + (size_t)b*128*HWs;   // MODE1 channel base

  // ---- compute ids ----
  const int w   = tid >> 6;
  const int ln  = tid & 63;
  const int l15 = ln & 15, lg = ln >> 4;
  const int wmb = (BN==128)? ((w>>1)*64) : ((w&3)*32);
  const int wnb = (BN==128)? ((w&1)*64) : 0;

  f4v acc[MF][NF];
  #pragma unroll
  for (int i=0;i<MF;i++)
    #pragma unroll
    for (int j=0;j<NF;j++)
      #pragma unroll
      for (int q=0;q<4;q++) acc[i][j][q] = 0.0f;

  for (int k0 = 0; k0 < K; k0 += 32){
    // ---- gather 16 A-values for (sm, k0+sk .. +16) ----
    ushortT hv[16];
    if (MODE != 1){
      int kb = k0 + sk;
      int c = kb/9, rr = kb - c*9;
      int dy = rr/3, dx = rr - dy*3;
      #pragma unroll
      for (int kk=0; kk<16; kk++){
        int yy = y + dy - 1, xx = x + dx - 1;
        bool v = ((unsigned)yy < 80u) & ((unsigned)xx < 80u);
        long off = (long)c*HWs + (dy-1)*80 + (dx-1);
        const float* bp = (c < Cin0)? a0p : a1p;
        float val = 0.0f;
        if (MODE == 0){
          val = v ? bp[off] : 0.0f;
        } else {
          if (v){
            float gv = gp[(dy-1)*80 + (dx-1)];
            float scl = (c < Cin0)? gv : (1.0f - gv);
            val = scl * bp[off];
          }
        }
        hv[kk] = f2bf(val);
        dx++; if (dx==3){ dx=0; dy++; if (dy==3){ dy=0; c++; } }
      }
    } else {
      int kb = k0 + sk;
      int r  = kb >> 7;        // kernel point 0..8
      int c0 = kb & 127;
      float oy = ofb[(size_t)(2*r)*HWs];
      float ox = ofb[(size_t)(2*r+1)*HWs];
      float mk = sigm_(ofb[(size_t)(18+r)*HWs]);
      int dy = r/3, dx = r - dy*3;
      float ys = oy + (float)(y + dy - 1);
      float xs = ox + (float)(x + dx - 1);
      float yf = floorf(ys), xf = floorf(xs);
      float wy = ys - yf, wx = xs - xf;
      int y0 = (int)yf, x0 = (int)xf;
      float vy0 = ((unsigned)y0     < 80u)? 1.f : 0.f;
      float vy1 = ((unsigned)(y0+1) < 80u)? 1.f : 0.f;
      float vx0 = ((unsigned)x0     < 80u)? 1.f : 0.f;
      float vx1 = ((unsigned)(x0+1) < 80u)? 1.f : 0.f;
      float w00 = (1.f-wy)*(1.f-wx)*mk*vy0*vx0;
      float w01 = (1.f-wy)*wx      *mk*vy0*vx1;
      float w10 = wy      *(1.f-wx)*mk*vy1*vx0;
      float w11 = wy      *wx      *mk*vy1*vx1;
      int cy0 = min(max(y0  ,0),79), cy1 = min(max(y0+1,0),79);
      int cx0 = min(max(x0  ,0),79), cx1 = min(max(x0+1,0),79);
      const float* q00 = irb + (size_t)c0*HWs + cy0*80+cx0;
      const float* q01 = irb + (size_t)c0*HWs + cy0*80+cx1;
      const float* q10 = irb + (size_t)c0*HWs + cy1*80+cx0;
      const float* q11 = irb + (size_t)c0*HWs + cy1*80+cx1;
      #pragma unroll
      for (int kk=0; kk<16; kk++){
        float v = w00*q00[0] + w01*q01[0] + w10*q10[0] + w11*q11[0];
        hv[kk] = f2bf(v);
        q00 += HWs; q01 += HWs; q10 += HWs; q11 += HWs;
      }
    }
    // ---- B chunk loads (bf16 global, 16B per chunk) ----
    uint4 bchunk[BCH];
    #pragma unroll
    for (int i=0;i<BCH;i++){
      int ch = tid + i*256;
      if (BN==128 || tid < 128){
        int n = ch >> 2, kc = (ch & 3) << 3;
        bchunk[i] = *(const uint4*)(Bt + (size_t)n*K + k0 + kc);
      }
    }

    __syncthreads();
    *(s8v*)&As[sm*40 + sk    ] = *(const s8v*)&hv[0];
    *(s8v*)&As[sm*40 + sk + 8] = *(const s8v*)&hv[8];
    #pragma unroll
    for (int i=0;i<BCH;i++){
      int ch = tid + i*256;
      if (BN==128 || tid < 128){
        int n = ch >> 2, kc = (ch & 3) << 3;
        *(uint4*)&Bs[n*40 + kc] = bchunk[i];
      }
    }
    __syncthreads();

    // ---- fragments + MFMA ----
    s8v af[MF], bfr[NF];
    #pragma unroll
    for (int i=0;i<MF;i++) af[i]  = *(const s8v*)&As[(wmb + i*16 + l15)*40 + lg*8];
    #pragma unroll
    for (int j=0;j<NF;j++) bfr[j] = *(const s8v*)&Bs[(wnb + j*16 + l15)*40 + lg*8];
    #pragma unroll
    for (int i=0;i<MF;i++)
      #pragma unroll
      for (int j=0;j<NF;j++)
        acc[i][j] = __builtin_amdgcn_mfma_f32_16x16x32_bf16(af[i], bfr[j], acc[i][j], 0, 0, 0);
  }

  // ---- epilogue: lane holds D rows 4*lg..4*lg+3 (consecutive m), col = l15 ----
  float rsv = (EPI==3)? rsp[0] : 0.0f;
  #pragma unroll
  for (int i=0;i<MF;i++){
    int m0 = mb + wmb + i*16 + 4*lg;
    int p0 = m0 - b*HWs;
    #pragma unroll
    for (int j=0;j<NF;j++){
      int n = wnb + j*16 + l15;
      if (BN==32 && n >= Nout) continue;
      size_t ob = ((size_t)b*Nout + n)*HWs + p0;
      float vv[4];
      #pragma unroll
      for (int q=0;q<4;q++) vv[q] = acc[i][j][q];
      if (EPI == 0){
        float bb = e0[n];
        #pragma unroll
        for (int q=0;q<4;q++) vv[q] += bb;
      } else if (EPI == 1){
        float bb = e0[n];
        #pragma unroll
        for (int q=0;q<4;q++) vv[q] = silu_(vv[q] + bb);
      } else if (EPI == 2){
        float s = e0[n], sh = e1[n];
        #pragma unroll
        for (int q=0;q<4;q++) vv[q] = silu_(fmaf(vv[q], s, sh));
      } else {
        float s = e0[n], sh = e1[n];
        float4 r4 = *(const float4*)(res + ob);
        float rr[4] = {r4.x, r4.y, r4.z, r4.w};
        #pragma unroll
        for (int q=0;q<4;q++) vv[q] = silu_(fmaf(vv[q], s, sh)) + rsv*rr[q];
      }
      float4 o4; o4.x=vv[0]; o4.y=vv[1]; o4.z=vv[2]; o4.w=vv[3];
      *(float4*)(Out + ob) = o4;
    }
  }
}

// ---------------- gate conv1x1 256->16 + bn + silu ----------------
__global__ __launch_bounds__(256) void gate1_kernel(
  const float* __restrict__ rgb, const float* __restrict__ iral,
  const float* __restrict__ wg1, const float* __restrict__ bns,
  float* __restrict__ out)
{
  __shared__ float Ws[4096];   // [c][mc]
  int tid = threadIdx.x;
  for (int i = tid; i < 4096; i += 256){
    int mc = i >> 8, c = i & 255;
    Ws[c*16 + mc] = wg1[i];
  }
  __syncthreads();
  int idx = blockIdx.x*256 + tid;
  int b = idx / HWs, p = idx - b*HWs;
  const float* r0 = rgb  + (size_t)b*128*HWs + p;
  const float* i0 = iral + ((size_t)b*128 - 128)*HWs + p;
  float acc[16];
  #pragma unroll
  for (int mc=0;mc<16;mc++) acc[mc]=0.f;
  #pragma unroll 4
  for (int c=0;c<256;c++){
    float v = (c<128) ? r0[(size_t)c*HWs] : i0[(size_t)c*HWs];
    const float4* w4 = (const float4*)&Ws[c*16];
    #pragma unroll
    for (int q=0;q<4;q++){
      float4 w = w4[q];
      acc[q*4+0] = fmaf(v, w.x, acc[q*4+0]);
      acc[q*4+1] = fmaf(v, w.y, acc[q*4+1]);
      acc[q*4+2] = fmaf(v, w.z, acc[q*4+2]);
      acc[q*4+3] = fmaf(v, w.w, acc[q*4+3]);
    }
  }
  #pragma unroll
  for (int mc=0;mc<16;mc++){
    float t = fmaf(acc[mc], bns[mc], bns[16+mc]);
    out[((size_t)b*16+mc)*HWs + p] = silu_(t);
  }
}

// ---------------- gate depthwise3x3+bn+silu + conv1x1->1 + sigmoid ----------------
__global__ __launch_bounds__(256) void gate23_kernel(
  const float* __restrict__ g1b, const float* __restrict__ wg2,
  const float* __restrict__ wg3, const float* __restrict__ bg3,
  const float* __restrict__ bns, float* __restrict__ g)
{
  __shared__ float w2s[144], w3s[16], sc2[16], sh2[16];
  __shared__ float b3s;
  int tid = threadIdx.x;
  if (tid < 144) w2s[tid] = wg2[tid];
  if (tid < 16){ w3s[tid] = wg3[tid]; sc2[tid] = bns[32+tid]; sh2[tid] = bns[48+tid]; }
  if (tid == 0) b3s = bg3[0];
  __syncthreads();
  int idx = blockIdx.x*256 + tid;
  int b = idx / HWs, p = idx - b*HWs;
  int y = p/80, x = p - y*80;
  float acc = b3s;
  #pragma unroll
  for (int mc=0;mc<16;mc++){
    const float* base = g1b + ((size_t)b*16+mc)*HWs;
    float s = 0.f;
    #pragma unroll
    for (int r=0;r<9;r++){
      int dy = r/3, dx = r - (r/3)*3;
      int yy = y + dy - 1, xx = x + dx - 1;
      if (((unsigned)yy < 80u) & ((unsigned)xx < 80u))
        s = fmaf(base[yy*80+xx], w2s[mc*9+r], s);
    }
    float t = fmaf(s, sc2[mc], sh2[mc]);
    acc = fmaf(silu_(t), w3s[mc], acc);
  }
  g[idx] = sigm_(acc);
}

extern "C" void kernel_launch(void* const* d_in, const int* in_sizes, int n_in,
                              void* d_out, int out_size, void* d_ws, size_t ws_size,
                              hipStream_t stream)
{
  const float* rgb  = (const float*)d_in[0];
  const float* ir   = (const float*)d_in[1];
  const float* w1   = (const float*)d_in[2];
  const float* b1   = (const float*)d_in[3];
  const float* w2   = (const float*)d_in[4];
  const float* b2   = (const float*)d_in[5];
  const float* wd   = (const float*)d_in[6];
  const float* bd   = (const float*)d_in[7];
  const float* wg1  = (const float*)d_in[8];
  const float* bng1 = (const float*)d_in[9];
  const float* wg2  = (const float*)d_in[10];
  const float* bng2 = (const float*)d_in[11];
  const float* wg3  = (const float*)d_in[12];
  const float* bg3  = (const float*)d_in[13];
  const float* wf   = (const float*)d_in[14];
  const float* bnf  = (const float*)d_in[15];
  const float* rs   = (const float*)d_in[16];
  float* out = (float*)d_out;

  float* ws   = (float*)d_ws;
  float* hbuf = ws;                    // 6,553,600 f
  float* offb = hbuf + 6553600;        // 1,382,400 f
  float* iral = offb + 1382400;        // 6,553,600 f
  float* g1b  = iral + 6553600;        //   819,200 f
  float* gbuf = g1b  + 819200;         //    51,200 f
  float* bns  = gbuf + 51200;          //       320 f
  ushortT* Bt1 = (ushortT*)(bns + 320);        // 128*2304 = 294,912 ush
  ushortT* Bt2 = Bt1 + 294912;                 //  32*1152 =  36,864 ush
  ushortT* Bt3 = Bt2 + 36864;                  // 128*1152 = 147,456 ush
  ushortT* Bt4 = Bt3 + 147456;                 // 128*2304 = 294,912 ush
  // total ~62 MB

  bnprep_kernel<<<1, 256, 0, stream>>>(bng1, bng2, bnf, bns);
  wtb_kernel<<<(294912+255)/256, 256, 0, stream>>>(w1, Bt1, 256, 128, 128, 2304, 0);
  wtb_kernel<<<( 36864+255)/256, 256, 0, stream>>>(w2, Bt2, 128,  27,  32, 1152, 0);
  wtb_kernel<<<(147456+255)/256, 256, 0, stream>>>(wd, Bt3, 128, 128, 128, 1152, 1);
  wtb_kernel<<<(294912+255)/256, 256, 0, stream>>>(wf, Bt4, 256, 128, 128, 2304, 0);

  // h = silu(conv3x3(cat(rgb,ir), w_off1) + b_off1)
  mconv<0,128,1><<<400, 256, 0, stream>>>(rgb, ir, 128, 256, nullptr,
      Bt1, 2304, hbuf, 128, b1, nullptr, nullptr, nullptr);
  // off = conv3x3(h, w_off2) + b_off2   (27 ch raw)
  mconv<0,32,0><<<400, 256, 0, stream>>>(hbuf, hbuf, 128, 128, nullptr,
      Bt2, 1152, offb, 27, b2, nullptr, nullptr, nullptr);
  // ir_aligned = DCN(ir, offsets, mask) + b_dcn   (fused bilinear gather)
  mconv<1,128,0><<<400, 256, 0, stream>>>(ir, ir, 128, 128, offb,
      Bt3, 1152, iral, 128, bd, nullptr, nullptr, nullptr);
  // gate path
  gate1_kernel<<<200, 256, 0, stream>>>(rgb, iral, wg1, bns, g1b);
  gate23_kernel<<<200, 256, 0, stream>>>(g1b, wg2, wg3, bg3, bns, gbuf);
  // out = silu(bn(conv3x3(concat(g*ir_al,(1-g)*rgb), w_f))) + res_scale*ir_aligned
  mconv<2,128,3><<<400, 256, 0, stream>>>(iral, rgb, 128, 256, gbuf,
      Bt4, 2304, out, 128, bns+64, bns+192, iral, rs);
}

// Round 9
// 928.927 us; speedup vs baseline: 1.8625x; 1.2578x over previous
//
#include <hip/hip_runtime.h>
#include <math.h>

#define HWs 6400

typedef __attribute__((ext_vector_type(8))) short s8v;
typedef __attribute__((ext_vector_type(4))) float f4v;
typedef unsigned short ushortT;
typedef unsigned int uintT;

__device__ __forceinline__ float sigm_(float x){ return 1.0f/(1.0f+__expf(-x)); }
__device__ __forceinline__ float silu_(float x){ return x/(1.0f+__expf(-x)); }
__device__ __forceinline__ ushortT f2bf(float f){
  uintT u = __float_as_uint(f);
  u = (u + 0x7fffu + ((u>>16)&1u)) >> 16;
  return (ushortT)u;
}

// ---------------- weight prep: w[OC][Cin][3][3] -> Bt[n][k] bf16, k = r*Cin + c ----------------
__global__ void wtb_kernel(const float* __restrict__ w, ushortT* __restrict__ Bt,
                           int lcin, int OC, int Npad, int K){
  int idx = blockIdx.x*256 + threadIdx.x;
  if (idx >= Npad*K) return;
  int n = idx / K, k = idx - n*K;
  int r = k >> lcin, c = k & ((1<<lcin)-1);
  float v = (n < OC) ? w[(((size_t)n << lcin) + c)*9 + r] : 0.0f;
  Bt[idx] = f2bf(v);
}

// ---------------- bn scale/shift prep ----------------
// layout: [0:16] sc1 [16:32] sh1 [32:48] sc2 [48:64] sh2 [64:192] scF [192:320] shF
__global__ void bnprep_kernel(const float* __restrict__ bn1, const float* __restrict__ bn2,
                              const float* __restrict__ bnf, float* __restrict__ o){
  int t = threadIdx.x;
  if (t < 16){
    float s = bn1[t] / sqrtf(bn1[48+t] + 1e-5f);
    o[t] = s; o[16+t] = bn1[16+t] - bn1[32+t]*s;
  } else if (t < 32){
    int i = t-16;
    float s = bn2[i] / sqrtf(bn2[48+i] + 1e-5f);
    o[32+i] = s; o[48+i] = bn2[16+i] - bn2[32+i]*s;
  } else if (t < 160){
    int i = t-32;
    float s = bnf[i] / sqrtf(bnf[384+i] + 1e-5f);
    o[64+i] = s; o[192+i] = bnf[128+i] - bnf[256+i]*s;
  }
}

// ---------------- MFMA implicit-GEMM conv, k = r*Cin + c ----------------
// BM=64, BK=32, 256 thr = 4 waves. Grid = 51200/64 = 800 blocks.
// BN=128: waves 2x2, wave tile 32x64 (MF=2,NF=4). BN=32: waves 4x1, tile 16x32 (MF=1,NF=2).
// Staging: thread (sm=tid&63, kg=tid>>6) gathers 8 k for row sm; r,c0 wave-uniform.
// MODE 0: 3x3 conv on concat(A0[Cin0], rest from A1)
// MODE 1: deformable bilinear gather on A0 (=ir, 128ch), offsets offp
// MODE 2: MODE0 with gate scale: c<Cin0 -> g, else 1-g (g = offp, 1 plane/batch)
// EPI: 0 +bias ; 1 silu(x+bias) ; 2 silu(x*sc+sh) ; 3 silu(x*sc+sh)+rs*res
template<int MODE, int BN, int EPI, int LCIN>
__global__ __launch_bounds__(256,4)
void mconv(const float* __restrict__ A0, const float* __restrict__ A1,
           int Cin0,
           const float* __restrict__ offp,
           const ushortT* __restrict__ Bt, int K,
           float* __restrict__ Out, int Nout,
           const float* __restrict__ e0, const float* __restrict__ e1,
           const float* __restrict__ res, const float* __restrict__ rsp)
{
  constexpr int CINM = (1<<LCIN) - 1;
  constexpr int MF = (BN==128)? 2 : 1;
  constexpr int NF = (BN==128)? 4 : 2;
  constexpr int BCH = (BN==128)? 2 : 1;
  __shared__ ushortT As[64*40];
  __shared__ ushortT Bs[BN*40];

  const int tid = threadIdx.x;
  const int mb  = blockIdx.x * 64;
  const int b   = mb / HWs;            // uniform, blocks never straddle batches
  const int sm  = tid & 63;
  const int kg  = tid >> 6;            // wave-uniform 0..3
  const int p   = mb - b*HWs + sm;
  const int y   = p / 80;
  const int x   = p - y*80;

  const float* a0p = A0 + (size_t)b*Cin0*HWs + p;
  const float* a1p = (MODE!=1)? (A1 + ((size_t)b*((1<<LCIN)-Cin0) - (size_t)Cin0)*HWs + p) : A0;
  const float* gp  = (MODE==2)? (offp + (size_t)b*HWs + p) : A0;
  const float* ofb = (MODE==1)? (offp + (size_t)b*27*HWs + p) : A0;
  const float* irb = A0 + (size_t)b*128*HWs;    // MODE1: image base (abs pixel offsets)

  // compute ids
  const int ln  = tid & 63;
  const int l15 = ln & 15, lg = ln >> 4;
  const int wv  = tid >> 6;
  const int wmb = (BN==128)? ((wv>>1)*32) : (wv*16);
  const int wnb = (BN==128)? ((wv&1)*64) : 0;

  f4v acc[MF][NF];
  #pragma unroll
  for (int i=0;i<MF;i++)
    #pragma unroll
    for (int j=0;j<NF;j++)
      #pragma unroll
      for (int q=0;q<4;q++) acc[i][j][q] = 0.0f;

  // MODE1 cached bilinear state (valid between r-changes)
  float w00=0.f,w01=0.f,w10=0.f,w11=0.f;
  int o00=0,o01=0,o10=0,o11=0;
  // MODE2 cached gate value for current r
  float gvr = 0.f;

  for (int k0 = 0; k0 < K; k0 += 32){
    const int kb = k0 + kg*8;
    const int r  = kb >> LCIN;         // wave-uniform
    const int c0 = kb & CINM;          // wave-uniform
    s8v h;

    if (MODE != 1){
      const int r3 = r/3;
      const int dy = r3 - 1, dx = r - r3*3 - 1;
      const int yy = y + dy, xx = x + dx;
      const bool v = ((unsigned)yy < 80u) & ((unsigned)xx < 80u);
      const float* bp = (c0 < Cin0)? a0p : a1p;
      const float* q = bp + (size_t)c0*HWs + (dy*80 + dx);
      float scl = 1.0f;
      if (MODE == 2){
        if ((k0 & CINM) == 0){         // r changed -> reload gate value
          gvr = v ? gp[dy*80 + dx] : 0.0f;
        }
        scl = (c0 < Cin0)? gvr : (1.0f - gvr);
      }
      if (v){
        #pragma unroll
        for (int kk=0;kk<8;kk++){
          float val = q[(size_t)kk*HWs];
          if (MODE == 2) val *= scl;
          h[kk] = (short)f2bf(val);
        }
      } else {
        #pragma unroll
        for (int kk=0;kk<8;kk++) h[kk] = 0;
      }
    } else {
      if ((k0 & 127) == 0){            // r changed -> recompute bilinear state
        float oy = ofb[(size_t)(2*r)*HWs];
        float ox = ofb[(size_t)(2*r+1)*HWs];
        float mk = sigm_(ofb[(size_t)(18+r)*HWs]);
        int r3 = r/3;
        int dy = r3, dx = r - r3*3;
        float ys = oy + (float)(y + dy - 1);
        float xs = ox + (float)(x + dx - 1);
        float yf = floorf(ys), xf = floorf(xs);
        float wy = ys - yf, wx = xs - xf;
        int y0 = (int)yf, x0 = (int)xf;
        float vy0 = ((unsigned)y0     < 80u)? 1.f : 0.f;
        float vy1 = ((unsigned)(y0+1) < 80u)? 1.f : 0.f;
        float vx0 = ((unsigned)x0     < 80u)? 1.f : 0.f;
        float vx1 = ((unsigned)(x0+1) < 80u)? 1.f : 0.f;
        w00 = (1.f-wy)*(1.f-wx)*mk*vy0*vx0;
        w01 = (1.f-wy)*wx      *mk*vy0*vx1;
        w10 = wy      *(1.f-wx)*mk*vy1*vx0;
        w11 = wy      *wx      *mk*vy1*vx1;
        int cy0 = min(max(y0  ,0),79), cy1 = min(max(y0+1,0),79);
        int cx0 = min(max(x0  ,0),79), cx1 = min(max(x0+1,0),79);
        o00 = cy0*80+cx0; o01 = cy0*80+cx1; o10 = cy1*80+cx0; o11 = cy1*80+cx1;
      }
      const float* q00 = irb + (size_t)c0*HWs + o00;
      const float* q01 = irb + (size_t)c0*HWs + o01;
      const float* q10 = irb + (size_t)c0*HWs + o10;
      const float* q11 = irb + (size_t)c0*HWs + o11;
      #pragma unroll
      for (int kk=0;kk<8;kk++){
        float val = w00*q00[(size_t)kk*HWs] + w01*q01[(size_t)kk*HWs]
                  + w10*q10[(size_t)kk*HWs] + w11*q11[(size_t)kk*HWs];
        h[kk] = (short)f2bf(val);
      }
    }

    // B chunk loads (bf16 global -> regs)
    uint4 bchunk[BCH];
    #pragma unroll
    for (int i=0;i<BCH;i++){
      int ch = tid + i*256;
      if (BN==128 || tid < 128){
        int n = ch >> 2, kc = (ch & 3) << 3;
        bchunk[i] = *(const uint4*)(Bt + (size_t)n*K + k0 + kc);
      }
    }

    __syncthreads();
    *(s8v*)&As[sm*40 + kg*8] = h;
    #pragma unroll
    for (int i=0;i<BCH;i++){
      int ch = tid + i*256;
      if (BN==128 || tid < 128){
        int n = ch >> 2, kc = (ch & 3) << 3;
        *(uint4*)&Bs[n*40 + kc] = bchunk[i];
      }
    }
    __syncthreads();

    // fragments + MFMA
    s8v af[MF], bfr[NF];
    #pragma unroll
    for (int i=0;i<MF;i++) af[i]  = *(const s8v*)&As[(wmb + i*16 + l15)*40 + lg*8];
    #pragma unroll
    for (int j=0;j<NF;j++) bfr[j] = *(const s8v*)&Bs[(wnb + j*16 + l15)*40 + lg*8];
    #pragma unroll
    for (int i=0;i<MF;i++)
      #pragma unroll
      for (int j=0;j<NF;j++)
        acc[i][j] = __builtin_amdgcn_mfma_f32_16x16x32_bf16(af[i], bfr[j], acc[i][j], 0, 0, 0);
    __syncthreads();
  }

  // epilogue: lane holds rows 4*lg..+3 (consecutive m), col = l15
  float rsv = (EPI==3)? rsp[0] : 0.0f;
  #pragma unroll
  for (int i=0;i<MF;i++){
    int p0 = (mb - b*HWs) + wmb + i*16 + 4*lg;
    #pragma unroll
    for (int j=0;j<NF;j++){
      int n = wnb + j*16 + l15;
      if (BN==32 && n >= Nout) continue;
      size_t ob = ((size_t)b*Nout + n)*HWs + p0;
      float vv[4];
      #pragma unroll
      for (int q=0;q<4;q++) vv[q] = acc[i][j][q];
      if (EPI == 0){
        float bb = e0[n];
        #pragma unroll
        for (int q=0;q<4;q++) vv[q] += bb;
      } else if (EPI == 1){
        float bb = e0[n];
        #pragma unroll
        for (int q=0;q<4;q++) vv[q] = silu_(vv[q] + bb);
      } else if (EPI == 2){
        float s = e0[n], sh = e1[n];
        #pragma unroll
        for (int q=0;q<4;q++) vv[q] = silu_(fmaf(vv[q], s, sh));
      } else {
        float s = e0[n], sh = e1[n];
        float4 r4 = *(const float4*)(res + ob);
        float rr[4] = {r4.x, r4.y, r4.z, r4.w};
        #pragma unroll
        for (int q=0;q<4;q++) vv[q] = silu_(fmaf(vv[q], s, sh)) + rsv*rr[q];
      }
      float4 o4; o4.x=vv[0]; o4.y=vv[1]; o4.z=vv[2]; o4.w=vv[3];
      *(float4*)(Out + ob) = o4;
    }
  }
}

// ---------------- gate conv1x1 256->16 + bn + silu ----------------
__global__ __launch_bounds__(256) void gate1_kernel(
  const float* __restrict__ rgb, const float* __restrict__ iral,
  const float* __restrict__ wg1, const float* __restrict__ bns,
  float* __restrict__ out)
{
  __shared__ float Ws[4096];   // [c][mc]
  int tid = threadIdx.x;
  for (int i = tid; i < 4096; i += 256){
    int mc = i >> 8, c = i & 255;
    Ws[c*16 + mc] = wg1[i];
  }
  __syncthreads();
  int idx = blockIdx.x*256 + tid;
  int b = idx / HWs, p = idx - b*HWs;
  const float* r0 = rgb  + (size_t)b*128*HWs + p;
  const float* i0 = iral + ((size_t)b*128 - 128)*HWs + p;
  float acc[16];
  #pragma unroll
  for (int mc=0;mc<16;mc++) acc[mc]=0.f;
  #pragma unroll 4
  for (int c=0;c<256;c++){
    float v = (c<128) ? r0[(size_t)c*HWs] : i0[(size_t)c*HWs];
    const float4* w4 = (const float4*)&Ws[c*16];
    #pragma unroll
    for (int q=0;q<4;q++){
      float4 w = w4[q];
      acc[q*4+0] = fmaf(v, w.x, acc[q*4+0]);
      acc[q*4+1] = fmaf(v, w.y, acc[q*4+1]);
      acc[q*4+2] = fmaf(v, w.z, acc[q*4+2]);
      acc[q*4+3] = fmaf(v, w.w, acc[q*4+3]);
    }
  }
  #pragma unroll
  for (int mc=0;mc<16;mc++){
    float t = fmaf(acc[mc], bns[mc], bns[16+mc]);
    out[((size_t)b*16+mc)*HWs + p] = silu_(t);
  }
}

// ---------------- gate depthwise3x3+bn+silu + conv1x1->1 + sigmoid ----------------
__global__ __launch_bounds__(256) void gate23_kernel(
  const float* __restrict__ g1b, const float* __restrict__ wg2,
  const float* __restrict__ wg3, const float* __restrict__ bg3,
  const float* __restrict__ bns, float* __restrict__ g)
{
  __shared__ float w2s[144], w3s[16], sc2[16], sh2[16];
  __shared__ float b3s;
  int tid = threadIdx.x;
  if (tid < 144) w2s[tid] = wg2[tid];
  if (tid < 16){ w3s[tid] = wg3[tid]; sc2[tid] = bns[32+tid]; sh2[tid] = bns[48+tid]; }
  if (tid == 0) b3s = bg3[0];
  __syncthreads();
  int idx = blockIdx.x*256 + tid;
  int b = idx / HWs, p = idx - b*HWs;
  int y = p/80, x = p - y*80;
  float acc = b3s;
  #pragma unroll
  for (int mc=0;mc<16;mc++){
    const float* base = g1b + ((size_t)b*16+mc)*HWs;
    float s = 0.f;
    #pragma unroll
    for (int r=0;r<9;r++){
      int dy = r/3, dx = r - (r/3)*3;
      int yy = y + dy - 1, xx = x + dx - 1;
      if (((unsigned)yy < 80u) & ((unsigned)xx < 80u))
        s = fmaf(base[yy*80+xx], w2s[mc*9+r], s);
    }
    float t = fmaf(s, sc2[mc], sh2[mc]);
    acc = fmaf(silu_(t), w3s[mc], acc);
  }
  g[idx] = sigm_(acc);
}

extern "C" void kernel_launch(void* const* d_in, const int* in_sizes, int n_in,
                              void* d_out, int out_size, void* d_ws, size_t ws_size,
                              hipStream_t stream)
{
  const float* rgb  = (const float*)d_in[0];
  const float* ir   = (const float*)d_in[1];
  const float* w1   = (const float*)d_in[2];
  const float* b1   = (const float*)d_in[3];
  const float* w2   = (const float*)d_in[4];
  const float* b2   = (const float*)d_in[5];
  const float* wd   = (const float*)d_in[6];
  const float* bd   = (const float*)d_in[7];
  const float* wg1  = (const float*)d_in[8];
  const float* bng1 = (const float*)d_in[9];
  const float* wg2  = (const float*)d_in[10];
  const float* bng2 = (const float*)d_in[11];
  const float* wg3  = (const float*)d_in[12];
  const float* bg3  = (const float*)d_in[13];
  const float* wf   = (const float*)d_in[14];
  const float* bnf  = (const float*)d_in[15];
  const float* rs   = (const float*)d_in[16];
  float* out = (float*)d_out;

  float* ws   = (float*)d_ws;
  float* hbuf = ws;                    // 6,553,600 f
  float* offb = hbuf + 6553600;        // 1,382,400 f
  float* iral = offb + 1382400;        // 6,553,600 f
  float* g1b  = iral + 6553600;        //   819,200 f
  float* gbuf = g1b  + 819200;         //    51,200 f
  float* bns  = gbuf + 51200;          //       320 f
  ushortT* Bt1 = (ushortT*)(bns + 320);        // 128*2304
  ushortT* Bt2 = Bt1 + 294912;                 //  32*1152
  ushortT* Bt3 = Bt2 + 36864;                  // 128*1152
  ushortT* Bt4 = Bt3 + 147456;                 // 128*2304
  // total ~62 MB

  bnprep_kernel<<<1, 256, 0, stream>>>(bng1, bng2, bnf, bns);
  wtb_kernel<<<(294912+255)/256, 256, 0, stream>>>(w1, Bt1, 8, 128, 128, 2304);
  wtb_kernel<<<( 36864+255)/256, 256, 0, stream>>>(w2, Bt2, 7,  27,  32, 1152);
  wtb_kernel<<<(147456+255)/256, 256, 0, stream>>>(wd, Bt3, 7, 128, 128, 1152);
  wtb_kernel<<<(294912+255)/256, 256, 0, stream>>>(wf, Bt4, 8, 128, 128, 2304);

  // h = silu(conv3x3(cat(rgb,ir), w_off1) + b_off1)
  mconv<0,128,1,8><<<800, 256, 0, stream>>>(rgb, ir, 128, nullptr,
      Bt1, 2304, hbuf, 128, b1, nullptr, nullptr, nullptr);
  // off = conv3x3(h, w_off2) + b_off2   (27 ch raw)
  mconv<0,32,0,7><<<800, 256, 0, stream>>>(hbuf, hbuf, 128, nullptr,
      Bt2, 1152, offb, 27, b2, nullptr, nullptr, nullptr);
  // ir_aligned = DCN(ir, offsets, mask) + b_dcn   (fused bilinear gather)
  mconv<1,128,0,7><<<800, 256, 0, stream>>>(ir, ir, 128, offb,
      Bt3, 1152, iral, 128, bd, nullptr, nullptr, nullptr);
  // gate path
  gate1_kernel<<<200, 256, 0, stream>>>(rgb, iral, wg1, bns, g1b);
  gate23_kernel<<<200, 256, 0, stream>>>(g1b, wg2, wg3, bg3, bns, gbuf);
  // out = silu(bn(conv3x3(concat(g*ir_al,(1-g)*rgb), w_f))) + res_scale*ir_aligned
  mconv<2,128,3,8><<<800, 256, 0, stream>>>(iral, rgb, 128, gbuf,
      Bt4, 2304, out, 128, bns+64, bns+192, iral, rs);
}